// Round 13
// baseline (1697.478 us; speedup 1.0000x reference)
//
#include <hip/hip_runtime.h>
#include <math.h>

// Router: cross-attn + LN + MLP scorer + top-p gather.
// R13: R12 (verified, 1431us) + producer-wave repack: carrying GEMMs run
//      320 threads; waves 0-3 = unchanged R12 GEMM, wave 4 repacks the next
//      stage's operand (Wk/Wv/Qcanon/W1a/W1b) -> 5 standalone repack
//      dispatches eliminated. Weight slots ping-pong WSA@0 / WSB@192MiB.
//      Fallback R3 path if workspace too small.

#define LV   2048
#define LT   1024
#define DIM  4096
#define NHD  16
#define HDD  256
#define MLPH 8192

typedef __attribute__((ext_vector_type(8))) short bfx8;
typedef __attribute__((ext_vector_type(4))) float fx4;
typedef unsigned short u16;

// ---------------- wave helpers ----------------
__device__ __forceinline__ float wave_sum(float v){
#pragma unroll
  for (int o = 32; o > 0; o >>= 1) v += __shfl_xor(v, o);
  return v;
}
__device__ __forceinline__ float wave_max(float v){
#pragma unroll
  for (int o = 32; o > 0; o >>= 1) v = fmaxf(v, __shfl_xor(v, o));
  return v;
}

// split 8 fp32 into hi/lo bf16 (truncation; lo captures the residual)
__device__ __forceinline__ void splitpack(const float4 a, const float4 b,
                                          bfx8* hi, bfx8* lo){
  float f[8] = {a.x,a.y,a.z,a.w, b.x,b.y,b.z,b.w};
  union { bfx8 v; unsigned u[4]; } H, L;
#pragma unroll
  for (int p = 0; p < 4; ++p){
    unsigned u0 = __float_as_uint(f[2*p]);
    unsigned u1 = __float_as_uint(f[2*p+1]);
    H.u[p] = (u0 >> 16) | (u1 & 0xffff0000u);
    float h0 = __uint_as_float(u0 & 0xffff0000u);
    float h1 = __uint_as_float(u1 & 0xffff0000u);
    unsigned v0 = __float_as_uint(f[2*p]   - h0);
    unsigned v1 = __float_as_uint(f[2*p+1] - h1);
    L.u[p] = (v0 >> 16) | (v1 & 0xffff0000u);
  }
  *hi = H.v; *lo = L.v;
}

// async global->LDS, 16B per lane; lds dest = wave-uniform base + lane*16
__device__ __forceinline__ void glds16(const void* g, void* l){
  __builtin_amdgcn_global_load_lds(
      (const __attribute__((address_space(1))) unsigned int*)g,
      (__attribute__((address_space(3))) unsigned int*)l, 16, 0, 0);
}

// square-region XCD swizzle (XCD = id & 7 round-robin)
__device__ __forceinline__ void xcd_swizzle(int id, int nwg, int nx,
                                            int* bm, int* bn){
  const int my = nwg / nx;
  if (((nx & 3) == 0) && ((my & 1) == 0) && ((nwg & 7) == 0)){
    const int rm = my >> 1, rn = nx >> 2;
    const int x  = id & 7;
    const int j  = id >> 3;
    *bm = ((x >> 2) * rm) + j / rn;
    *bn = ((x & 3) * rn) + j % rn;
  } else if (((my & 7) == 0) && ((nwg & 7) == 0)){
    const int rm = my >> 3;
    const int x = id & 7, j = id >> 3;
    *bm = x * rm + j / nx;
    *bn = j % nx;
  } else { *bm = id / nx; *bn = id % nx; }
}

// ---------------- repack: fp32 [R][Kc] -> canonical hi/lo bf16 --------------
// canonical: 1KB tiles (16 rows x 32 k). tile T = rt*(Kc/32)+kt; within tile
// lane L (0..63) holds row rt*16+(L&15), k oct kt*32+(L>>4)*8, 8 elems.
__global__ __launch_bounds__(256)
void repack_kernel(const float* __restrict__ src, u16* __restrict__ hi,
                   u16* __restrict__ lo, int Kc, int ktsh)
{
  const long long e = ((long long)blockIdx.x * 256 + threadIdx.x) * 8;
  const int T = (int)(e >> 9);
  const int L = (int)(e >> 3) & 63;
  const int rt = T >> ktsh, kt = T & ((1 << ktsh) - 1);
  const int r = (rt << 4) + (L & 15);
  const int k = (kt << 5) + ((L >> 4) << 3);
  const float* p = src + (long long)r * Kc + k;
  bfx8 h, l;
  splitpack(*(const float4*)p, *(const float4*)(p + 4), &h, &l);
  *(bfx8*)(hi + e) = h;
  *(bfx8*)(lo + e) = l;
}

// ---------------- MFMA GEMM on canonical operands (NT, 16x16x32) ------------
// R12-verified core; 256 threads, 4 waves.
template<int GELU, int TRANSC>
__global__ __launch_bounds__(256)
void mgemm(const u16* __restrict__ Ah, const u16* __restrict__ Al, int aKT, long long aZe,
           const u16* __restrict__ Bh, const u16* __restrict__ Bl, int bKT, long long bZe,
           float* __restrict__ C, int ldc, long long cZe,
           const float* __restrict__ bias,
           int nx, int KT, int kt0, int zkt, float alpha)
{
  __shared__ bfx8 lbuf[2][32][64];
  const int tid  = threadIdx.x;
  const int lane = tid & 63;
  const int wv   = tid >> 6;
  const int wr   = wv >> 1, wc = wv & 1;
  int bm, bn;
  xcd_swizzle(blockIdx.x, gridDim.x, nx, &bm, &bn);
  const int m0 = bm << 7;
  const int n0 = bn << 7;
  const int z    = blockIdx.z;
  const u16* Ahz = Ah + (long long)z * aZe;
  const u16* Alz = Al + (long long)z * aZe;
  const u16* Bhz = Bh + (long long)z * bZe;
  const u16* Blz = Bl + (long long)z * bZe;
  C += (long long)z * cZe;
  const int ktb  = kt0 + z * zkt;
  const int rtA0 = m0 >> 4, rtB0 = n0 >> 4;

  const fx4 zz = {0.f, 0.f, 0.f, 0.f};
  fx4 acc[4][4];
#pragma unroll
  for (int i = 0; i < 4; ++i)
#pragma unroll
    for (int j = 0; j < 4; ++j) acc[i][j] = zz;

  const u16* wbase = (wv == 0) ? Ahz : (wv == 1) ? Alz : (wv == 2) ? Bhz : Blz;
  const int  wrt0  = (wv < 2) ? rtA0 : rtB0;
  const int  wKT   = (wv < 2) ? aKT  : bKT;

#define STAGE(BUF, KTI)                                                        \
  {                                                                            \
    _Pragma("unroll")                                                          \
    for (int q = 0; q < 8; ++q){                                               \
      const u16* g = wbase + ((long long)(wrt0 + q) * wKT + (KTI)) * 512       \
                     + lane * 8;                                               \
      glds16((const void*)g, (void*)&lbuf[BUF][wv * 8 + q][0]);                \
    }                                                                          \
  }

  int cur = 0;
  STAGE(0, ktb);
  for (int t = 0; t < KT; ++t){
    __syncthreads();
    if (t + 1 < KT) STAGE(cur ^ 1, ktb + t + 1);
    bfx8 ah[4], al[4], bh[4], bl[4];
#pragma unroll
    for (int i = 0; i < 4; ++i){
      ah[i] = lbuf[cur][     wr*4 + i][lane];
      al[i] = lbuf[cur][ 8 + wr*4 + i][lane];
      bh[i] = lbuf[cur][16 + wc*4 + i][lane];
      bl[i] = lbuf[cur][24 + wc*4 + i][lane];
    }
#pragma unroll
    for (int i = 0; i < 4; ++i)
#pragma unroll
      for (int j = 0; j < 4; ++j){
        acc[i][j] = __builtin_amdgcn_mfma_f32_16x16x32_bf16(ah[i], bl[j], acc[i][j], 0, 0, 0);
        acc[i][j] = __builtin_amdgcn_mfma_f32_16x16x32_bf16(al[i], bh[j], acc[i][j], 0, 0, 0);
        acc[i][j] = __builtin_amdgcn_mfma_f32_16x16x32_bf16(ah[i], bh[j], acc[i][j], 0, 0, 0);
      }
    cur ^= 1;
  }
#undef STAGE

#pragma unroll
  for (int i = 0; i < 4; ++i){
    const int row0 = m0 + wr*64 + i*16 + ((lane >> 4) << 2);
#pragma unroll
    for (int j = 0; j < 4; ++j){
      const int col = n0 + wc*64 + j*16 + (lane & 15);
      const float bb = bias ? bias[col] : 0.0f;
      if (TRANSC){
        float4 o;
        o.x = alpha*acc[i][j][0] + bb;
        o.y = alpha*acc[i][j][1] + bb;
        o.z = alpha*acc[i][j][2] + bb;
        o.w = alpha*acc[i][j][3] + bb;
        *(float4*)(C + (size_t)col*ldc + row0) = o;
      } else {
#pragma unroll
        for (int r = 0; r < 4; ++r){
          float v = alpha*acc[i][j][r] + bb;
          if (GELU) v = 0.5f*v*(1.0f + erff(v*0.70710678f));
          C[(size_t)(row0 + r)*ldc + col] = v;
        }
      }
    }
  }
}

// ---------------- mgemm_p: R12 core + 5th producer wave ---------------------
// 320 threads. Waves 0-3: identical GEMM. Wave 4: repack psrc (fp32 [R][4096])
// -> canonical phi/plo, pTPB tiles per block (pTPB <= KT), one tile per
// K-step with 1-deep prefetch. Same barrier count on every wave.
template<int GELU, int TRANSC>
__global__ __launch_bounds__(320)
void mgemm_p(const u16* __restrict__ Ah, const u16* __restrict__ Al, int aKT,
             const u16* __restrict__ Bh, const u16* __restrict__ Bl, int bKT,
             float* __restrict__ C, int ldc,
             const float* __restrict__ bias,
             int nx, int KT, float alpha,
             const float* __restrict__ psrc, u16* __restrict__ phi,
             u16* __restrict__ plo, int pTPB)
{
  __shared__ bfx8 lbuf[2][32][64];
  const int tid  = threadIdx.x;
  const int lane = tid & 63;
  const int wv   = tid >> 6;            // 0..4
  const int wr   = wv >> 1, wc = wv & 1;
  int bm, bn;
  xcd_swizzle(blockIdx.x, gridDim.x, nx, &bm, &bn);
  const int m0 = bm << 7;
  const int n0 = bn << 7;
  const int rtA0 = m0 >> 4, rtB0 = n0 >> 4;

  const fx4 zz = {0.f, 0.f, 0.f, 0.f};
  fx4 acc[4][4];
#pragma unroll
  for (int i = 0; i < 4; ++i)
#pragma unroll
    for (int j = 0; j < 4; ++j) acc[i][j] = zz;

  const u16* wbase = (wv == 0) ? Ah : (wv == 1) ? Al : (wv == 2) ? Bh : Bl;
  const int  wrt0  = (wv < 2) ? rtA0 : rtB0;
  const int  wKT   = (wv < 2) ? aKT  : bKT;

#define STAGE(BUF, KTI)                                                        \
  {                                                                            \
    _Pragma("unroll")                                                          \
    for (int q = 0; q < 8; ++q){                                               \
      const u16* g = wbase + ((long long)(wrt0 + q) * wKT + (KTI)) * 512       \
                     + lane * 8;                                               \
      glds16((const void*)g, (void*)&lbuf[BUF][wv * 8 + q][0]);                \
    }                                                                          \
  }

  // producer state (wave 4 only)
  const int Tbase = blockIdx.x * pTPB;
  float4 c0, c1;
  if (wv == 4 && pTPB > 0){
    const int T = Tbase;
    const float* p = psrc + (long long)(((T >> 7) << 4) + (lane & 15)) * 4096
                     + (((T & 127) << 5) + ((lane >> 4) << 3));
    c0 = *(const float4*)p;
    c1 = *(const float4*)(p + 4);
  }

  int cur = 0;
  if (wv < 4) STAGE(0, 0);
  for (int t = 0; t < KT; ++t){
    __syncthreads();                       // all 5 waves, KT barriers each
    if (wv < 4){
      if (t + 1 < KT) STAGE(cur ^ 1, t + 1);
      bfx8 ah[4], al[4], bh[4], bl[4];
#pragma unroll
      for (int i = 0; i < 4; ++i){
        ah[i] = lbuf[cur][     wr*4 + i][lane];
        al[i] = lbuf[cur][ 8 + wr*4 + i][lane];
        bh[i] = lbuf[cur][16 + wc*4 + i][lane];
        bl[i] = lbuf[cur][24 + wc*4 + i][lane];
      }
#pragma unroll
      for (int i = 0; i < 4; ++i)
#pragma unroll
        for (int j = 0; j < 4; ++j){
          acc[i][j] = __builtin_amdgcn_mfma_f32_16x16x32_bf16(ah[i], bl[j], acc[i][j], 0, 0, 0);
          acc[i][j] = __builtin_amdgcn_mfma_f32_16x16x32_bf16(al[i], bh[j], acc[i][j], 0, 0, 0);
          acc[i][j] = __builtin_amdgcn_mfma_f32_16x16x32_bf16(ah[i], bh[j], acc[i][j], 0, 0, 0);
        }
    } else if (t < pTPB){
      // process prefetched tile Tbase+t, then prefetch Tbase+t+1
      bfx8 h, l;
      splitpack(c0, c1, &h, &l);
      const long long e = (long long)(Tbase + t) * 512 + lane * 8;
      *(bfx8*)(phi + e) = h;
      *(bfx8*)(plo + e) = l;
      if (t + 1 < pTPB){
        const int T = Tbase + t + 1;
        const float* p = psrc + (long long)(((T >> 7) << 4) + (lane & 15)) * 4096
                         + (((T & 127) << 5) + ((lane >> 4) << 3));
        c0 = *(const float4*)p;
        c1 = *(const float4*)(p + 4);
      }
    }
    cur ^= 1;
  }
#undef STAGE

  if (wv < 4){
#pragma unroll
    for (int i = 0; i < 4; ++i){
      const int row0 = m0 + wr*64 + i*16 + ((lane >> 4) << 2);
#pragma unroll
      for (int j = 0; j < 4; ++j){
        const int col = n0 + wc*64 + j*16 + (lane & 15);
        const float bb = bias ? bias[col] : 0.0f;
        if (TRANSC){
          float4 o;
          o.x = alpha*acc[i][j][0] + bb;
          o.y = alpha*acc[i][j][1] + bb;
          o.z = alpha*acc[i][j][2] + bb;
          o.w = alpha*acc[i][j][3] + bb;
          *(float4*)(C + (size_t)col*ldc + row0) = o;
        } else {
#pragma unroll
          for (int r = 0; r < 4; ++r){
            float v = alpha*acc[i][j][r] + bb;
            if (GELU) v = 0.5f*v*(1.0f + erff(v*0.70710678f));
            C[(size_t)(row0 + r)*ldc + col] = v;
          }
        }
      }
    }
  }
}

// ---------------- fallback GEMM (R3, in-loop split) -------------------------
template<int GELU, int TRANSC>
__global__ __launch_bounds__(256)
void mgemm_fb(const float* __restrict__ A, long long aZ, int lda,
              const float* __restrict__ B, long long bZ, int ldb,
              float* __restrict__ C, long long cZ, int ldc,
              const float* __restrict__ bias, int Kd, float alpha)
{
  __shared__ bfx8 AhS[512], AlS[512], BhS[512], BlS[512];
  const int tid  = threadIdx.x;
  const int lane = tid & 63;
  const int wv   = tid >> 6;
  const int wr   = wv >> 1, wc = wv & 1;
  const int m0 = blockIdx.y * 128, n0 = blockIdx.x * 128;
  A += (long long)blockIdx.z * aZ;
  B += (long long)blockIdx.z * bZ;
  C += (long long)blockIdx.z * cZ;

  const fx4 zz = {0.f, 0.f, 0.f, 0.f};
  fx4 acc[4][4];
#pragma unroll
  for (int i = 0; i < 4; ++i)
#pragma unroll
    for (int j = 0; j < 4; ++j) acc[i][j] = zz;

  for (int k0 = 0; k0 < Kd; k0 += 32){
    __syncthreads();
#pragma unroll
    for (int pass = 0; pass < 2; ++pass){
      const int s = pass*256 + tid;
      const int m = ((s >> 6) << 4) + (s & 15);
      const int j = (s >> 4) & 3;
      const float* pA = A + (size_t)(m0 + m)*lda + k0 + j*8;
      splitpack(*(const float4*)pA, *(const float4*)(pA + 4), &AhS[s], &AlS[s]);
      const float* pB = B + (size_t)(n0 + m)*ldb + k0 + j*8;
      splitpack(*(const float4*)pB, *(const float4*)(pB + 4), &BhS[s], &BlS[s]);
    }
    __syncthreads();
    bfx8 ah[4], al[4], bh[4], bl[4];
#pragma unroll
    for (int i = 0; i < 4; ++i){
      ah[i] = AhS[(wr*4 + i)*64 + lane];
      al[i] = AlS[(wr*4 + i)*64 + lane];
      bh[i] = BhS[(wc*4 + i)*64 + lane];
      bl[i] = BlS[(wc*4 + i)*64 + lane];
    }
#pragma unroll
    for (int i = 0; i < 4; ++i)
#pragma unroll
      for (int j = 0; j < 4; ++j){
        acc[i][j] = __builtin_amdgcn_mfma_f32_16x16x32_bf16(ah[i], bl[j], acc[i][j], 0, 0, 0);
        acc[i][j] = __builtin_amdgcn_mfma_f32_16x16x32_bf16(al[i], bh[j], acc[i][j], 0, 0, 0);
        acc[i][j] = __builtin_amdgcn_mfma_f32_16x16x32_bf16(ah[i], bh[j], acc[i][j], 0, 0, 0);
      }
  }
#pragma unroll
  for (int i = 0; i < 4; ++i){
    const int row0 = m0 + wr*64 + i*16 + ((lane >> 4) << 2);
#pragma unroll
    for (int j = 0; j < 4; ++j){
      const int col = n0 + wc*64 + j*16 + (lane & 15);
      const float bb = bias ? bias[col] : 0.0f;
      if (TRANSC){
        float4 o;
        o.x = alpha*acc[i][j][0] + bb;
        o.y = alpha*acc[i][j][1] + bb;
        o.z = alpha*acc[i][j][2] + bb;
        o.w = alpha*acc[i][j][3] + bb;
        *(float4*)(C + (size_t)col*ldc + row0) = o;
      } else {
#pragma unroll
        for (int r = 0; r < 4; ++r){
          float v = alpha*acc[i][j][r] + bb;
          if (GELU) v = 0.5f*v*(1.0f + erff(v*0.70710678f));
          C[(size_t)(row0 + r)*ldc + col] = v;
        }
      }
    }
  }
}

// ---------------- softmax (fp32 in) -> canonical hi/lo P --------------------
__global__ __launch_bounds__(128)
void softmax_pack(const float* __restrict__ Lf, u16* __restrict__ ph,
                  u16* __restrict__ pl)
{
  __shared__ float rr[4];
  const int tid = threadIdx.x;
  const int h = blockIdx.x >> 11;
  const int m = blockIdx.x & 2047;
  const float* row = Lf + ((long long)h * 2048 + m) * 1024;
  const int k = tid * 8;
  float4 a = *(const float4*)(row + k);
  float4 b = *(const float4*)(row + k + 4);
  float v[8] = {a.x,a.y,a.z,a.w, b.x,b.y,b.z,b.w};
  float mx = v[0];
#pragma unroll
  for (int i = 1; i < 8; ++i) mx = fmaxf(mx, v[i]);
  mx = wave_max(mx);
  if ((tid & 63) == 0) rr[tid >> 6] = mx;
  __syncthreads();
  const float M = fmaxf(rr[0], rr[1]);
  float e[8], s = 0.0f;
#pragma unroll
  for (int i = 0; i < 8; ++i){ e[i] = expf(v[i] - M); s += e[i]; }
  s = wave_sum(s);
  if ((tid & 63) == 0) rr[2 + (tid >> 6)] = s;
  __syncthreads();
  const float S = rr[2] + rr[3];
  float4 p0 = make_float4(e[0]/S, e[1]/S, e[2]/S, e[3]/S);
  float4 p1 = make_float4(e[4]/S, e[5]/S, e[6]/S, e[7]/S);
  bfx8 hh, ll;
  splitpack(p0, p1, &hh, &ll);
  const int tile = (m >> 4) * 32 + (k >> 5);
  const int Lw = ((k >> 3) & 3) * 16 + (m & 15);
  const long long eoff = (long long)h * (2048ll*1024) + (long long)tile * 512 + Lw * 8;
  *(bfx8*)(ph + eoff) = hh;
  *(bfx8*)(pl + eoff) = ll;
}

// ---------------- softmax fallback (fp32 in-place, R3) ----------------------
__global__ __launch_bounds__(256)
void softmax_fb(float* __restrict__ X)
{
  __shared__ float r[8];
  const int tid = threadIdx.x;
  float* row = X + (size_t)blockIdx.x * 1024;
  float4 v = ((const float4*)row)[tid];
  float m = fmaxf(fmaxf(v.x,v.y), fmaxf(v.z,v.w));
  m = wave_max(m);
  if ((tid & 63) == 0) r[tid >> 6] = m;
  __syncthreads();
  m = fmaxf(fmaxf(r[0],r[1]), fmaxf(r[2],r[3]));
  float e0 = expf(v.x - m), e1 = expf(v.y - m), e2 = expf(v.z - m), e3 = expf(v.w - m);
  float s = (e0 + e1) + (e2 + e3);
  s = wave_sum(s);
  if ((tid & 63) == 0) r[4 + (tid >> 6)] = s;
  __syncthreads();
  s = (r[4] + r[5]) + (r[6] + r[7]);
  ((float4*)row)[tid] = make_float4(e0/s, e1/s, e2/s, e3/s);
}

// ---------------- residual + LayerNorm; PACK=1 writes canonical hi/lo -------
template<int PACK>
__global__ __launch_bounds__(256)
void ln_kernel(const float* __restrict__ vis, const float* ao, float* xnf,
               u16* __restrict__ xh, u16* __restrict__ xl,
               const float* __restrict__ w, const float* __restrict__ b)
{
  __shared__ float r[8];
  __shared__ float stat[2];
  const int tid = threadIdx.x;
  const int m = blockIdx.x;
  const size_t base = (size_t)m * DIM + tid * 16;
  float x[16];
#pragma unroll
  for (int q = 0; q < 4; ++q){
    float4 a = *(const float4*)(vis + base + q*4);
    float4 c = *(const float4*)(ao  + base + q*4);
    x[q*4+0]=a.x+c.x; x[q*4+1]=a.y+c.y; x[q*4+2]=a.z+c.z; x[q*4+3]=a.w+c.w;
  }
  float s = 0.0f;
#pragma unroll
  for (int i = 0; i < 16; ++i) s += x[i];
  s = wave_sum(s);
  if ((tid & 63) == 0) r[tid >> 6] = s;
  __syncthreads();
  if (tid == 0) stat[0] = (r[0]+r[1]+r[2]+r[3]) * (1.0f/4096.0f);
  __syncthreads();
  const float mu = stat[0];
  float vs = 0.0f;
#pragma unroll
  for (int i = 0; i < 16; ++i){ float d = x[i]-mu; vs += d*d; }
  vs = wave_sum(vs);
  if ((tid & 63) == 0) r[4 + (tid >> 6)] = vs;
  __syncthreads();
  if (tid == 0) stat[1] = (r[4]+r[5]+r[6]+r[7]) * (1.0f/4096.0f);
  __syncthreads();
  const float inv = 1.0f / sqrtf(stat[1] + 1e-5f);
  const int col = tid * 16;
  float o[16];
#pragma unroll
  for (int q = 0; q < 4; ++q){
    float4 wv = *(const float4*)(w + col + q*4);
    float4 bv = *(const float4*)(b + col + q*4);
    o[q*4+0] = (x[q*4+0]-mu)*inv*wv.x + bv.x;
    o[q*4+1] = (x[q*4+1]-mu)*inv*wv.y + bv.y;
    o[q*4+2] = (x[q*4+2]-mu)*inv*wv.z + bv.z;
    o[q*4+3] = (x[q*4+3]-mu)*inv*wv.w + bv.w;
  }
  if (PACK){
#pragma unroll
    for (int q = 0; q < 2; ++q){
      const int k = col + q*8;
      float4 p0 = make_float4(o[q*8+0], o[q*8+1], o[q*8+2], o[q*8+3]);
      float4 p1 = make_float4(o[q*8+4], o[q*8+5], o[q*8+6], o[q*8+7]);
      bfx8 hh, ll;
      splitpack(p0, p1, &hh, &ll);
      const int tile = (m >> 4) * 128 + (k >> 5);
      const int Lw = ((k >> 3) & 3) * 16 + (m & 15);
      const long long e = (long long)tile * 512 + Lw * 8;
      *(bfx8*)(xh + e) = hh;
      *(bfx8*)(xl + e) = ll;
    }
  } else {
#pragma unroll
    for (int q = 0; q < 4; ++q)
      *(float4*)(xnf + base + q*4) = make_float4(o[q*4+0],o[q*4+1],o[q*4+2],o[q*4+3]);
  }
}

// ---------------- scorer ----------------
__global__ __launch_bounds__(256)
void score_kernel(const float* __restrict__ H1, const float* __restrict__ W2v,
                  const float* __restrict__ b2, const float* __restrict__ noise,
                  float* __restrict__ sc)
{
  __shared__ float r[4];
  const int tid = threadIdx.x;
  const float* h = H1 + (size_t)blockIdx.x * MLPH + tid * 32;
  const float* w = W2v + tid * 32;
  float s = 0.0f;
#pragma unroll
  for (int q = 0; q < 8; ++q){
    float4 a = *(const float4*)(h + q*4);
    float4 c = *(const float4*)(w + q*4);
    s += a.x*c.x + a.y*c.y + a.z*c.z + a.w*c.w;
  }
  s = wave_sum(s);
  if ((tid & 63) == 0) r[tid >> 6] = s;
  __syncthreads();
  if (tid == 0) sc[blockIdx.x] = (r[0]+r[1]+r[2]+r[3]) + b2[0] + noise[blockIdx.x]*0.07f;
}

// ---------------- selection (1024 threads, verified) ----------------
__global__ __launch_bounds__(1024)
void select_kernel(const float* __restrict__ scores,
                   int* __restrict__ ord, int* __restrict__ kcount)
{
  __shared__ float sv[LV];
  __shared__ int   si[LV];
  __shared__ float red[32];
  __shared__ float stat[2];
  const int tid = threadIdx.x;
  for (int i = tid; i < LV; i += 1024){ sv[i] = scores[i] / 0.05f; si[i] = i; }
  __syncthreads();
  float m = -3.4e38f;
  for (int i = tid; i < LV; i += 1024) m = fmaxf(m, sv[i]);
  m = wave_max(m);
  if ((tid & 63) == 0) red[tid >> 6] = m;
  __syncthreads();
  if (tid == 0){
    float M = red[0];
    for (int w = 1; w < 16; ++w) M = fmaxf(M, red[w]);
    stat[0] = M;
  }
  __syncthreads();
  const float ymax = stat[0];
  float d = 0.0f;
  for (int i = tid; i < LV; i += 1024) d += expf(sv[i] - ymax);
  d = wave_sum(d);
  if ((tid & 63) == 0) red[16 + (tid >> 6)] = d;
  __syncthreads();
  if (tid == 0){
    float D = 0.0f;
    for (int w = 0; w < 16; ++w) D += red[16 + w];
    stat[1] = D;
  }
  __syncthreads();
  const float denom = stat[1];
  for (int size = 2; size <= LV; size <<= 1){
    for (int stride = size >> 1; stride > 0; stride >>= 1){
      __syncthreads();
      const int i = 2*tid - (tid & (stride - 1));
      const int j = i + stride;
      const bool up = ((i & size) == 0);
      float a = sv[i], b = sv[j];
      if ((a < b) == up){
        sv[i] = b; sv[j] = a;
        int ti = si[i]; si[i] = si[j]; si[j] = ti;
      }
    }
  }
  __syncthreads();
  for (int i = tid; i < LV; i += 1024) sv[i] = expf(sv[i] - ymax) / denom;
  __syncthreads();
  if (tid == 0){
    float c = 0.0f; int kc = LV;
    for (int j = 0; j < LV; ++j){
      c += sv[j];
      if (!((double)c <= 0.6)){ kc = j; break; }
    }
    *kcount = kc;
  }
  __syncthreads();
  for (int i = tid; i < LV; i += 1024) ord[i] = si[i];
}

// ---------------- output writer ----------------
__global__ __launch_bounds__(256)
void writer_kernel(const float* __restrict__ vis, const int* __restrict__ ord,
                   const int* __restrict__ kc, float* __restrict__ out)
{
  const int j = blockIdx.x;
  float4* dst = (float4*)(out + (size_t)j * DIM);
  if (j < kc[0]){
    const float4* src = (const float4*)(vis + (size_t)ord[j] * DIM);
    for (int i = threadIdx.x; i < DIM/4; i += 256) dst[i] = src[i];
  } else {
    const float4 z4 = make_float4(0.f,0.f,0.f,0.f);
    for (int i = threadIdx.x; i < DIM/4; i += 256) dst[i] = z4;
  }
}

// ---------------- launch ----------------
extern "C" void kernel_launch(void* const* d_in, const int* in_sizes, int n_in,
                              void* d_out, int out_size, void* d_ws, size_t ws_size,
                              hipStream_t stream)
{
  (void)in_sizes; (void)n_in; (void)out_size;
  const float* vis  = (const float*)d_in[0];
  const float* txt  = (const float*)d_in[1];
  const float* mask = (const float*)d_in[2];
  const float* noise= (const float*)d_in[3];
  const float* Wq = (const float*)d_in[4];  const float* bq = (const float*)d_in[5];
  const float* Wk = (const float*)d_in[6];  const float* bk = (const float*)d_in[7];
  const float* Wv = (const float*)d_in[8];  const float* bv = (const float*)d_in[9];
  const float* Wo = (const float*)d_in[10]; const float* bo = (const float*)d_in[11];
  const float* lw = (const float*)d_in[12]; const float* lb = (const float*)d_in[13];
  const float* W1 = (const float*)d_in[14]; const float* b1 = (const float*)d_in[15];
  const float* W2 = (const float*)d_in[16]; const float* b2 = (const float*)d_in[17];
  float* out = (float*)d_out;
  const dim3 blk(256);
  const dim3 blkp(320);
  const size_t MiB = 1u << 20;

  // pick Hc (heads per attention group)
  int Hc = 0;
  for (int h = 16; h >= 1; h >>= 1){
    size_t need = (192 + 16 * (size_t)h) * MiB;
    if (need <= ws_size){ Hc = h; break; }
  }

  if (Hc > 0){
    // workspace map (R12 layout; WSB lives in the attention-only Lf region):
    //  WSA: 0-64 (weight ping)   WSB: 192-256 (weight pong, Lf-region)
    //  TMPf 64-96; QC 96-128; VC 128-160; TC 160-176; KF 176-192 / VTC 176-192
    //  VTF 192-208 (over dead Wk); Lf 192+; PC after Lf; H1f 128-192; XN 96-128
    char* B0 = (char*)d_ws;
    u16* WAh  = (u16*)(B0 + 0);          u16* WAl  = (u16*)(B0 + 32*MiB);
    u16* WBh  = (u16*)(B0 + 192*MiB);    u16* WBl  = (u16*)(B0 + 224*MiB);
    float* TMPf = (float*)(B0 + 64*MiB);
    u16* QCh  = (u16*)(B0 + 96*MiB);     u16* QCl  = (u16*)(B0 + 112*MiB);
    u16* VCh  = (u16*)(B0 + 128*MiB);    u16* VCl  = (u16*)(B0 + 144*MiB);
    u16* TCh  = (u16*)(B0 + 160*MiB);    u16* TCl  = (u16*)(B0 + 168*MiB);
    float* KF  = (float*)(B0 + 176*MiB);
    float* VTF = (float*)(B0 + 192*MiB);
    u16* VTCh = (u16*)(B0 + 176*MiB);    u16* VTCl = (u16*)(B0 + 184*MiB);
    float* Lf  = (float*)(B0 + 192*MiB);
    u16* PCh  = (u16*)(B0 + (192 + (size_t)Hc*8)*MiB);
    u16* PCl  = (u16*)(B0 + (192 + (size_t)Hc*12)*MiB);
    float* H1f = (float*)(B0 + 128*MiB);
    u16* XNh  = (u16*)(B0 + 96*MiB);     u16* XNl  = (u16*)(B0 + 112*MiB);
    float* SCf = (float*)(B0 + 192*MiB);
    int* ORD = (int*)(SCf + LV);
    int* KCp = ORD + LV;

    // canonicalize inputs + first weight
    repack_kernel<<<dim3(4096), blk, 0, stream>>>(vis, VCh, VCl, 4096, 7);
    repack_kernel<<<dim3(2048), blk, 0, stream>>>(txt, TCh, TCl, 4096, 7);
    repack_kernel<<<dim3(8192), blk, 0, stream>>>(Wq, WAh, WAl, 4096, 7);
    // Q = vis @ Wq^T + bq ; producer repacks Wk -> WSB (32768/512 = 64 t/blk)
    mgemm_p<0,0><<<dim3(512,1,1), blkp, 0, stream>>>(VCh, VCl, 128, WAh, WAl, 128,
        TMPf, 4096, bq, 32, 128, 1.0f, Wk, WBh, WBl, 64);
    // K ; producer repacks Wv -> WSA (32768/256 = 128 t/blk = KT)
    mgemm_p<0,0><<<dim3(256,1,1), blkp, 0, stream>>>(TCh, TCl, 128, WBh, WBl, 128,
        KF, 4096, bk, 32, 128, 1.0f, Wv, WAh, WAl, 128);
    // V (transposed out) ; producer repacks Q(TMPf) -> QC (16384/256 = 64)
    mgemm_p<0,1><<<dim3(256,1,1), blkp, 0, stream>>>(TCh, TCl, 128, WAh, WAl, 128,
        VTF, 1024, bv, 32, 128, 1.0f, TMPf, QCh, QCl, 64);
    // remaining intermediate canonicalizations
    repack_kernel<<<dim3(2048), blk, 0, stream>>>(KF, TCh, TCl, 4096, 7);
    repack_kernel<<<dim3(2048), blk, 0, stream>>>(VTF, VTCh, VTCl, 1024, 5);
    // attention, Hc heads per group (unchanged R12 mgemm)
    const int NG = NHD / Hc;
    for (int g = 0; g < NG; ++g){
      mgemm<0,0><<<dim3(128,1,Hc), blk, 0, stream>>>(QCh, QCl, 128, 0, TCh, TCl, 128, 0,
          Lf, 1024, 2097152ll, mask, 8, 8, g*Hc*8, 8, 0.0625f);
      softmax_pack<<<dim3(Hc*2048), dim3(128), 0, stream>>>(Lf, PCh, PCl);
      mgemm<0,0><<<dim3(32,1,Hc), blk, 0, stream>>>(PCh, PCl, 32, 2097152ll,
          VTCh + (long long)g*Hc*262144, VTCl + (long long)g*Hc*262144, 32, 262144ll,
          TMPf + (long long)g*Hc*256, 4096, 256, nullptr, 2, 32, 0, 0, 1.0f);
    }
    // ctx -> canonical (into VC slot)
    repack_kernel<<<dim3(4096), blk, 0, stream>>>(TMPf, VCh, VCl, 4096, 7);
    // Wo -> WSA (Wv dead)
    repack_kernel<<<dim3(8192), blk, 0, stream>>>(Wo, WAh, WAl, 4096, 7);
    // attn_out = ctx @ Wo^T + bo ; producer repacks W1a -> WSB (Lf dead)
    mgemm_p<0,0><<<dim3(512,1,1), blkp, 0, stream>>>(VCh, VCl, 128, WAh, WAl, 128,
        TMPf, 4096, bo, 32, 128, 1.0f, W1, WBh, WBl, 64);
    // residual + LN -> XN canonical
    ln_kernel<1><<<dim3(LV), blk, 0, stream>>>(vis, TMPf, nullptr, XNh, XNl, lw, lb);
    // W1a-GEMM (B=WSB) ; producer repacks W1b -> WSA (Wo dead)
    mgemm_p<1,0><<<dim3(512,1,1), blkp, 0, stream>>>(XNh, XNl, 128, WBh, WBl, 128,
        H1f, 8192, b1, 32, 128, 1.0f, W1 + 16777216ll, WAh, WAl, 64);
    // W1b-GEMM (B=WSA)
    mgemm<1,0><<<dim3(512,1,1), blk, 0, stream>>>(XNh, XNl, 128, 0, WAh, WAl, 128, 0,
        H1f + 4096, 8192, 0, b1 + 4096, 32, 128, 0, 0, 1.0f);
    // scores, selection, output
    score_kernel<<<dim3(LV), blk, 0, stream>>>(H1f, W2, b2, noise, SCf);
    select_kernel<<<dim3(1), dim3(1024), 0, stream>>>(SCf, ORD, KCp);
    writer_kernel<<<dim3(LV), blk, 0, stream>>>(vis, ORD, KCp, out);
    return;
  }

  // ---------------- fallback path (R3, verified) ----------------------------
  float* ws = (float*)d_ws;
  const long long OQ  = 0;
  const long long OK_ = (long long)LV * DIM;
  const long long OV  = OK_ + (long long)LT * DIM;
  const long long OC  = OV  + (long long)LT * DIM;
  const long long OL  = OC  + (long long)LV * DIM;
  const long long LSTRIDE = (long long)LV * LT;
  int Hf = 16;
  while (Hf > 1){
    size_t need = (size_t)(OL + (long long)Hf * LSTRIDE + 8192) * 4;
    if (need <= ws_size) break;
    Hf >>= 1;
  }
  float* Qw  = ws + OQ;
  float* Kw  = ws + OK_;
  float* Vt  = ws + OV;
  float* Cw  = ws + OC;
  float* Lw  = ws + OL;
  float* H1w = ws + OK_;
  float* SCw = ws + OL + (long long)Hf * LSTRIDE;
  int*   ORDw = (int*)(SCw + LV);
  int*   KCw  = ORDw + LV;

  mgemm_fb<0,0><<<dim3(DIM/128, LV/128, 1), blk, 0, stream>>>(vis,0,DIM, Wq,0,DIM, Qw,0,DIM, bq, DIM, 1.0f);
  mgemm_fb<0,0><<<dim3(DIM/128, LT/128, 1), blk, 0, stream>>>(txt,0,DIM, Wk,0,DIM, Kw,0,DIM, bk, DIM, 1.0f);
  mgemm_fb<0,1><<<dim3(DIM/128, LT/128, 1), blk, 0, stream>>>(txt,0,DIM, Wv,0,DIM, Vt,0,LT, bv, DIM, 1.0f);
  for (int g = 0; g < NHD/Hf; ++g){
    const long long ho = (long long)g * Hf * HDD;
    mgemm_fb<0,0><<<dim3(LT/128, LV/128, Hf), blk, 0, stream>>>(
        Qw+ho, HDD, DIM,  Kw+ho, HDD, DIM,  Lw, LSTRIDE, LT,  mask, HDD, 0.0625f);
    softmax_fb<<<dim3(Hf*LV), blk, 0, stream>>>(Lw);
    mgemm_fb<0,0><<<dim3(HDD/128, LV/128, Hf), blk, 0, stream>>>(
        Lw, LSTRIDE, LT,  Vt + (ho*(long long)LT), (long long)HDD*LT, LT,
        Cw+ho, HDD, DIM,  nullptr, LT, 1.0f);
  }
  mgemm_fb<0,0><<<dim3(DIM/128, LV/128, 1), blk, 0, stream>>>(Cw,0,DIM, Wo,0,DIM, Qw,0,DIM, bo, DIM, 1.0f);
  ln_kernel<0><<<dim3(LV), blk, 0, stream>>>(vis, Qw, Qw, nullptr, nullptr, lw, lb);
  mgemm_fb<1,0><<<dim3(MLPH/128, LV/128, 1), blk, 0, stream>>>(Qw,0,DIM, W1,0,DIM, H1w,0,MLPH, b1, DIM, 1.0f);
  score_kernel<<<dim3(LV), blk, 0, stream>>>(H1w, W2, b2, noise, SCw);
  select_kernel<<<dim3(1), dim3(1024), 0, stream>>>(SCw, ORDw, KCw);
  writer_kernel<<<dim3(LV), blk, 0, stream>>>(vis, ORDw, KCw, out);
}

// Round 14
// 1429.986 us; speedup vs baseline: 1.1871x; 1.1871x over previous
//
#include <hip/hip_runtime.h>
#include <math.h>

// Router: cross-attn + LN + MLP scorer + top-p gather.
// FINAL (R12, verified 1431us): 16x16x32 bf16x3 canonical GEMM, glds staging,
// dbuf single-barrier K loop, square-region XCD swizzle, separate repacks,
// 1024-thread select. Fallback R3 path if workspace too small.
//
// Ledger: R5 32x32 shape (-9%, L2 thrash), R7 counted-vmcnt (-2%, sched pin),
// R8 epilogue fusion (-5%, VGPR), R9 single-buffer (-12%, exposed latency),
// R10/R11 B-split fusion (-29/-34%, conflicts/uncoalesced), R13 producer wave
// (-19%, barrier-coupled vmcnt drain). All reverted; R12 is the optimum.

#define LV   2048
#define LT   1024
#define DIM  4096
#define NHD  16
#define HDD  256
#define MLPH 8192

typedef __attribute__((ext_vector_type(8))) short bfx8;
typedef __attribute__((ext_vector_type(4))) float fx4;
typedef unsigned short u16;

// ---------------- wave helpers ----------------
__device__ __forceinline__ float wave_sum(float v){
#pragma unroll
  for (int o = 32; o > 0; o >>= 1) v += __shfl_xor(v, o);
  return v;
}
__device__ __forceinline__ float wave_max(float v){
#pragma unroll
  for (int o = 32; o > 0; o >>= 1) v = fmaxf(v, __shfl_xor(v, o));
  return v;
}

// split 8 fp32 into hi/lo bf16 (truncation; lo captures the residual)
__device__ __forceinline__ void splitpack(const float4 a, const float4 b,
                                          bfx8* hi, bfx8* lo){
  float f[8] = {a.x,a.y,a.z,a.w, b.x,b.y,b.z,b.w};
  union { bfx8 v; unsigned u[4]; } H, L;
#pragma unroll
  for (int p = 0; p < 4; ++p){
    unsigned u0 = __float_as_uint(f[2*p]);
    unsigned u1 = __float_as_uint(f[2*p+1]);
    H.u[p] = (u0 >> 16) | (u1 & 0xffff0000u);
    float h0 = __uint_as_float(u0 & 0xffff0000u);
    float h1 = __uint_as_float(u1 & 0xffff0000u);
    unsigned v0 = __float_as_uint(f[2*p]   - h0);
    unsigned v1 = __float_as_uint(f[2*p+1] - h1);
    L.u[p] = (v0 >> 16) | (v1 & 0xffff0000u);
  }
  *hi = H.v; *lo = L.v;
}

// async global->LDS, 16B per lane; lds dest = wave-uniform base + lane*16
__device__ __forceinline__ void glds16(const void* g, void* l){
  __builtin_amdgcn_global_load_lds(
      (const __attribute__((address_space(1))) unsigned int*)g,
      (__attribute__((address_space(3))) unsigned int*)l, 16, 0, 0);
}

// ---------------- repack: fp32 [R][Kc] -> canonical hi/lo bf16 --------------
// canonical: 1KB tiles (16 rows x 32 k). tile T = rt*(Kc/32)+kt; within tile
// lane L (0..63) holds row rt*16+(L&15), k oct kt*32+(L>>4)*8, 8 elems.
__global__ __launch_bounds__(256)
void repack_kernel(const float* __restrict__ src, u16* __restrict__ hi,
                   u16* __restrict__ lo, int Kc, int ktsh)
{
  const long long e = ((long long)blockIdx.x * 256 + threadIdx.x) * 8;
  const int T = (int)(e >> 9);
  const int L = (int)(e >> 3) & 63;
  const int rt = T >> ktsh, kt = T & ((1 << ktsh) - 1);
  const int r = (rt << 4) + (L & 15);
  const int k = (kt << 5) + ((L >> 4) << 3);
  const float* p = src + (long long)r * Kc + k;
  bfx8 h, l;
  splitpack(*(const float4*)p, *(const float4*)(p + 4), &h, &l);
  *(bfx8*)(hi + e) = h;
  *(bfx8*)(lo + e) = l;
}

// ---------------- MFMA GEMM on canonical operands (NT, 16x16x32) ------------
// C[m,n] = alpha * sum_k A[m,k]*B[n,k] + bias[n]; A,B canonical hi/lo.
// 128x128 tile, BK=32, 4 waves 2x2 (64x64/wave), bf16x3, glds staging,
// single-barrier double-buffered K loop, SQUARE-REGION XCD swizzle.
template<int GELU, int TRANSC>
__global__ __launch_bounds__(256)
void mgemm(const u16* __restrict__ Ah, const u16* __restrict__ Al, int aKT, long long aZe,
           const u16* __restrict__ Bh, const u16* __restrict__ Bl, int bKT, long long bZe,
           float* __restrict__ C, int ldc, long long cZe,
           const float* __restrict__ bias,
           int nx, int KT, int kt0, int zkt, float alpha)
{
  __shared__ bfx8 lbuf[2][32][64];   // [buf][tile u][lane]: u = mat*8+rt_local
  const int tid  = threadIdx.x;
  const int lane = tid & 63;
  const int wv   = tid >> 6;
  const int wr   = wv >> 1, wc = wv & 1;
  const int nwg  = gridDim.x;
  const int id   = blockIdx.x;
  // square-region XCD swizzle: HW dispatch is round-robin (XCD = id & 7).
  int bm, bn;
  {
    const int my = nwg / nx;
    if (((nx & 3) == 0) && ((my & 1) == 0) && ((nwg & 7) == 0)){
      const int rm = my >> 1, rn = nx >> 2;   // region dims in blocks
      const int x  = id & 7;                  // XCD
      const int j  = id >> 3;                 // index within region
      bm = ((x >> 2) * rm) + j / rn;
      bn = ((x & 3) * rn) + j % rn;
    } else if (((my & 7) == 0) && ((nwg & 7) == 0)){
      const int rm = my >> 3;
      const int x = id & 7, j = id >> 3;
      bm = x * rm + j / nx;
      bn = j % nx;
    } else { bm = id / nx; bn = id % nx; }
  }
  const int m0 = bm << 7;
  const int n0 = bn << 7;
  const int z    = blockIdx.z;
  const u16* Ahz = Ah + (long long)z * aZe;
  const u16* Alz = Al + (long long)z * aZe;
  const u16* Bhz = Bh + (long long)z * bZe;
  const u16* Blz = Bl + (long long)z * bZe;
  C += (long long)z * cZe;
  const int ktb  = kt0 + z * zkt;
  const int rtA0 = m0 >> 4, rtB0 = n0 >> 4;

  const fx4 zz = {0.f, 0.f, 0.f, 0.f};
  fx4 acc[4][4];
#pragma unroll
  for (int i = 0; i < 4; ++i)
#pragma unroll
    for (int j = 0; j < 4; ++j) acc[i][j] = zz;

  const u16* wbase = (wv == 0) ? Ahz : (wv == 1) ? Alz : (wv == 2) ? Bhz : Blz;
  const int  wrt0  = (wv < 2) ? rtA0 : rtB0;
  const int  wKT   = (wv < 2) ? aKT  : bKT;

#define STAGE(BUF, KTI)                                                        \
  {                                                                            \
    _Pragma("unroll")                                                          \
    for (int q = 0; q < 8; ++q){                                               \
      const u16* g = wbase + ((long long)(wrt0 + q) * wKT + (KTI)) * 512       \
                     + lane * 8;                                               \
      glds16((const void*)g, (void*)&lbuf[BUF][wv * 8 + q][0]);                \
    }                                                                          \
  }

  int cur = 0;
  STAGE(0, ktb);
  for (int t = 0; t < KT; ++t){
    __syncthreads();                       // drains vmcnt -> lbuf[cur] ready
    if (t + 1 < KT) STAGE(cur ^ 1, ktb + t + 1);
    bfx8 ah[4], al[4], bh[4], bl[4];
#pragma unroll
    for (int i = 0; i < 4; ++i){
      ah[i] = lbuf[cur][     wr*4 + i][lane];
      al[i] = lbuf[cur][ 8 + wr*4 + i][lane];
      bh[i] = lbuf[cur][16 + wc*4 + i][lane];
      bl[i] = lbuf[cur][24 + wc*4 + i][lane];
    }
#pragma unroll
    for (int i = 0; i < 4; ++i)
#pragma unroll
      for (int j = 0; j < 4; ++j){
        acc[i][j] = __builtin_amdgcn_mfma_f32_16x16x32_bf16(ah[i], bl[j], acc[i][j], 0, 0, 0);
        acc[i][j] = __builtin_amdgcn_mfma_f32_16x16x32_bf16(al[i], bh[j], acc[i][j], 0, 0, 0);
        acc[i][j] = __builtin_amdgcn_mfma_f32_16x16x32_bf16(ah[i], bh[j], acc[i][j], 0, 0, 0);
      }
    cur ^= 1;
  }
#undef STAGE

  // epilogue: D col = lane&15, row = (lane>>4)*4 + r   [m89, verified R3..R12]
#pragma unroll
  for (int i = 0; i < 4; ++i){
    const int row0 = m0 + wr*64 + i*16 + ((lane >> 4) << 2);
#pragma unroll
    for (int j = 0; j < 4; ++j){
      const int col = n0 + wc*64 + j*16 + (lane & 15);
      const float bb = bias ? bias[col] : 0.0f;
      if (TRANSC){
        float4 o;
        o.x = alpha*acc[i][j][0] + bb;
        o.y = alpha*acc[i][j][1] + bb;
        o.z = alpha*acc[i][j][2] + bb;
        o.w = alpha*acc[i][j][3] + bb;
        *(float4*)(C + (size_t)col*ldc + row0) = o;
      } else {
#pragma unroll
        for (int r = 0; r < 4; ++r){
          float v = alpha*acc[i][j][r] + bb;
          if (GELU) v = 0.5f*v*(1.0f + erff(v*0.70710678f));
          C[(size_t)(row0 + r)*ldc + col] = v;
        }
      }
    }
  }
}

// ---------------- fallback GEMM (R3, in-loop split) -------------------------
template<int GELU, int TRANSC>
__global__ __launch_bounds__(256)
void mgemm_fb(const float* __restrict__ A, long long aZ, int lda,
              const float* __restrict__ B, long long bZ, int ldb,
              float* __restrict__ C, long long cZ, int ldc,
              const float* __restrict__ bias, int Kd, float alpha)
{
  __shared__ bfx8 AhS[512], AlS[512], BhS[512], BlS[512];
  const int tid  = threadIdx.x;
  const int lane = tid & 63;
  const int wv   = tid >> 6;
  const int wr   = wv >> 1, wc = wv & 1;
  const int m0 = blockIdx.y * 128, n0 = blockIdx.x * 128;
  A += (long long)blockIdx.z * aZ;
  B += (long long)blockIdx.z * bZ;
  C += (long long)blockIdx.z * cZ;

  const fx4 zz = {0.f, 0.f, 0.f, 0.f};
  fx4 acc[4][4];
#pragma unroll
  for (int i = 0; i < 4; ++i)
#pragma unroll
    for (int j = 0; j < 4; ++j) acc[i][j] = zz;

  for (int k0 = 0; k0 < Kd; k0 += 32){
    __syncthreads();
#pragma unroll
    for (int pass = 0; pass < 2; ++pass){
      const int s = pass*256 + tid;
      const int m = ((s >> 6) << 4) + (s & 15);
      const int j = (s >> 4) & 3;
      const float* pA = A + (size_t)(m0 + m)*lda + k0 + j*8;
      splitpack(*(const float4*)pA, *(const float4*)(pA + 4), &AhS[s], &AlS[s]);
      const float* pB = B + (size_t)(n0 + m)*ldb + k0 + j*8;
      splitpack(*(const float4*)pB, *(const float4*)(pB + 4), &BhS[s], &BlS[s]);
    }
    __syncthreads();
    bfx8 ah[4], al[4], bh[4], bl[4];
#pragma unroll
    for (int i = 0; i < 4; ++i){
      ah[i] = AhS[(wr*4 + i)*64 + lane];
      al[i] = AlS[(wr*4 + i)*64 + lane];
      bh[i] = BhS[(wc*4 + i)*64 + lane];
      bl[i] = BlS[(wc*4 + i)*64 + lane];
    }
#pragma unroll
    for (int i = 0; i < 4; ++i)
#pragma unroll
      for (int j = 0; j < 4; ++j){
        acc[i][j] = __builtin_amdgcn_mfma_f32_16x16x32_bf16(ah[i], bl[j], acc[i][j], 0, 0, 0);
        acc[i][j] = __builtin_amdgcn_mfma_f32_16x16x32_bf16(al[i], bh[j], acc[i][j], 0, 0, 0);
        acc[i][j] = __builtin_amdgcn_mfma_f32_16x16x32_bf16(ah[i], bh[j], acc[i][j], 0, 0, 0);
      }
  }
#pragma unroll
  for (int i = 0; i < 4; ++i){
    const int row0 = m0 + wr*64 + i*16 + ((lane >> 4) << 2);
#pragma unroll
    for (int j = 0; j < 4; ++j){
      const int col = n0 + wc*64 + j*16 + (lane & 15);
      const float bb = bias ? bias[col] : 0.0f;
      if (TRANSC){
        float4 o;
        o.x = alpha*acc[i][j][0] + bb;
        o.y = alpha*acc[i][j][1] + bb;
        o.z = alpha*acc[i][j][2] + bb;
        o.w = alpha*acc[i][j][3] + bb;
        *(float4*)(C + (size_t)col*ldc + row0) = o;
      } else {
#pragma unroll
        for (int r = 0; r < 4; ++r){
          float v = alpha*acc[i][j][r] + bb;
          if (GELU) v = 0.5f*v*(1.0f + erff(v*0.70710678f));
          C[(size_t)(row0 + r)*ldc + col] = v;
        }
      }
    }
  }
}

// ---------------- softmax (fp32 in) -> canonical hi/lo P --------------------
__global__ __launch_bounds__(128)
void softmax_pack(const float* __restrict__ Lf, u16* __restrict__ ph,
                  u16* __restrict__ pl)
{
  __shared__ float rr[4];
  const int tid = threadIdx.x;
  const int h = blockIdx.x >> 11;
  const int m = blockIdx.x & 2047;
  const float* row = Lf + ((long long)h * 2048 + m) * 1024;
  const int k = tid * 8;
  float4 a = *(const float4*)(row + k);
  float4 b = *(const float4*)(row + k + 4);
  float v[8] = {a.x,a.y,a.z,a.w, b.x,b.y,b.z,b.w};
  float mx = v[0];
#pragma unroll
  for (int i = 1; i < 8; ++i) mx = fmaxf(mx, v[i]);
  mx = wave_max(mx);
  if ((tid & 63) == 0) rr[tid >> 6] = mx;
  __syncthreads();
  const float M = fmaxf(rr[0], rr[1]);
  float e[8], s = 0.0f;
#pragma unroll
  for (int i = 0; i < 8; ++i){ e[i] = expf(v[i] - M); s += e[i]; }
  s = wave_sum(s);
  if ((tid & 63) == 0) rr[2 + (tid >> 6)] = s;
  __syncthreads();
  const float S = rr[2] + rr[3];
  float4 p0 = make_float4(e[0]/S, e[1]/S, e[2]/S, e[3]/S);
  float4 p1 = make_float4(e[4]/S, e[5]/S, e[6]/S, e[7]/S);
  bfx8 hh, ll;
  splitpack(p0, p1, &hh, &ll);
  const int tile = (m >> 4) * 32 + (k >> 5);
  const int Lw = ((k >> 3) & 3) * 16 + (m & 15);
  const long long eoff = (long long)h * (2048ll*1024) + (long long)tile * 512 + Lw * 8;
  *(bfx8*)(ph + eoff) = hh;
  *(bfx8*)(pl + eoff) = ll;
}

// ---------------- softmax fallback (fp32 in-place, R3) ----------------------
__global__ __launch_bounds__(256)
void softmax_fb(float* __restrict__ X)
{
  __shared__ float r[8];
  const int tid = threadIdx.x;
  float* row = X + (size_t)blockIdx.x * 1024;
  float4 v = ((const float4*)row)[tid];
  float m = fmaxf(fmaxf(v.x,v.y), fmaxf(v.z,v.w));
  m = wave_max(m);
  if ((tid & 63) == 0) r[tid >> 6] = m;
  __syncthreads();
  m = fmaxf(fmaxf(r[0],r[1]), fmaxf(r[2],r[3]));
  float e0 = expf(v.x - m), e1 = expf(v.y - m), e2 = expf(v.z - m), e3 = expf(v.w - m);
  float s = (e0 + e1) + (e2 + e3);
  s = wave_sum(s);
  if ((tid & 63) == 0) r[4 + (tid >> 6)] = s;
  __syncthreads();
  s = (r[4] + r[5]) + (r[6] + r[7]);
  ((float4*)row)[tid] = make_float4(e0/s, e1/s, e2/s, e3/s);
}

// ---------------- residual + LayerNorm; PACK=1 writes canonical hi/lo -------
template<int PACK>
__global__ __launch_bounds__(256)
void ln_kernel(const float* __restrict__ vis, const float* ao, float* xnf,
               u16* __restrict__ xh, u16* __restrict__ xl,
               const float* __restrict__ w, const float* __restrict__ b)
{
  __shared__ float r[8];
  __shared__ float stat[2];
  const int tid = threadIdx.x;
  const int m = blockIdx.x;
  const size_t base = (size_t)m * DIM + tid * 16;
  float x[16];
#pragma unroll
  for (int q = 0; q < 4; ++q){
    float4 a = *(const float4*)(vis + base + q*4);
    float4 c = *(const float4*)(ao  + base + q*4);
    x[q*4+0]=a.x+c.x; x[q*4+1]=a.y+c.y; x[q*4+2]=a.z+c.z; x[q*4+3]=a.w+c.w;
  }
  float s = 0.0f;
#pragma unroll
  for (int i = 0; i < 16; ++i) s += x[i];
  s = wave_sum(s);
  if ((tid & 63) == 0) r[tid >> 6] = s;
  __syncthreads();
  if (tid == 0) stat[0] = (r[0]+r[1]+r[2]+r[3]) * (1.0f/4096.0f);
  __syncthreads();
  const float mu = stat[0];
  float vs = 0.0f;
#pragma unroll
  for (int i = 0; i < 16; ++i){ float d = x[i]-mu; vs += d*d; }
  vs = wave_sum(vs);
  if ((tid & 63) == 0) r[4 + (tid >> 6)] = vs;
  __syncthreads();
  if (tid == 0) stat[1] = (r[4]+r[5]+r[6]+r[7]) * (1.0f/4096.0f);
  __syncthreads();
  const float inv = 1.0f / sqrtf(stat[1] + 1e-5f);
  const int col = tid * 16;
  float o[16];
#pragma unroll
  for (int q = 0; q < 4; ++q){
    float4 wv = *(const float4*)(w + col + q*4);
    float4 bv = *(const float4*)(b + col + q*4);
    o[q*4+0] = (x[q*4+0]-mu)*inv*wv.x + bv.x;
    o[q*4+1] = (x[q*4+1]-mu)*inv*wv.y + bv.y;
    o[q*4+2] = (x[q*4+2]-mu)*inv*wv.z + bv.z;
    o[q*4+3] = (x[q*4+3]-mu)*inv*wv.w + bv.w;
  }
  if (PACK){
#pragma unroll
    for (int q = 0; q < 2; ++q){
      const int k = col + q*8;
      float4 p0 = make_float4(o[q*8+0], o[q*8+1], o[q*8+2], o[q*8+3]);
      float4 p1 = make_float4(o[q*8+4], o[q*8+5], o[q*8+6], o[q*8+7]);
      bfx8 hh, ll;
      splitpack(p0, p1, &hh, &ll);
      const int tile = (m >> 4) * 128 + (k >> 5);
      const int Lw = ((k >> 3) & 3) * 16 + (m & 15);
      const long long e = (long long)tile * 512 + Lw * 8;
      *(bfx8*)(xh + e) = hh;
      *(bfx8*)(xl + e) = ll;
    }
  } else {
#pragma unroll
    for (int q = 0; q < 4; ++q)
      *(float4*)(xnf + base + q*4) = make_float4(o[q*4+0],o[q*4+1],o[q*4+2],o[q*4+3]);
  }
}

// ---------------- scorer ----------------
__global__ __launch_bounds__(256)
void score_kernel(const float* __restrict__ H1, const float* __restrict__ W2v,
                  const float* __restrict__ b2, const float* __restrict__ noise,
                  float* __restrict__ sc)
{
  __shared__ float r[4];
  const int tid = threadIdx.x;
  const float* h = H1 + (size_t)blockIdx.x * MLPH + tid * 32;
  const float* w = W2v + tid * 32;
  float s = 0.0f;
#pragma unroll
  for (int q = 0; q < 8; ++q){
    float4 a = *(const float4*)(h + q*4);
    float4 c = *(const float4*)(w + q*4);
    s += a.x*c.x + a.y*c.y + a.z*c.z + a.w*c.w;
  }
  s = wave_sum(s);
  if ((tid & 63) == 0) r[tid >> 6] = s;
  __syncthreads();
  if (tid == 0) sc[blockIdx.x] = (r[0]+r[1]+r[2]+r[3]) + b2[0] + noise[blockIdx.x]*0.07f;
}

// ---------------- selection (1024 threads, verified) ----------------
__global__ __launch_bounds__(1024)
void select_kernel(const float* __restrict__ scores,
                   int* __restrict__ ord, int* __restrict__ kcount)
{
  __shared__ float sv[LV];
  __shared__ int   si[LV];
  __shared__ float red[32];
  __shared__ float stat[2];
  const int tid = threadIdx.x;
  for (int i = tid; i < LV; i += 1024){ sv[i] = scores[i] / 0.05f; si[i] = i; }
  __syncthreads();
  float m = -3.4e38f;
  for (int i = tid; i < LV; i += 1024) m = fmaxf(m, sv[i]);
  m = wave_max(m);
  if ((tid & 63) == 0) red[tid >> 6] = m;
  __syncthreads();
  if (tid == 0){
    float M = red[0];
    for (int w = 1; w < 16; ++w) M = fmaxf(M, red[w]);
    stat[0] = M;
  }
  __syncthreads();
  const float ymax = stat[0];
  float d = 0.0f;
  for (int i = tid; i < LV; i += 1024) d += expf(sv[i] - ymax);
  d = wave_sum(d);
  if ((tid & 63) == 0) red[16 + (tid >> 6)] = d;
  __syncthreads();
  if (tid == 0){
    float D = 0.0f;
    for (int w = 0; w < 16; ++w) D += red[16 + w];
    stat[1] = D;
  }
  __syncthreads();
  const float denom = stat[1];
  for (int size = 2; size <= LV; size <<= 1){
    for (int stride = size >> 1; stride > 0; stride >>= 1){
      __syncthreads();
      const int i = 2*tid - (tid & (stride - 1));
      const int j = i + stride;
      const bool up = ((i & size) == 0);
      float a = sv[i], b = sv[j];
      if ((a < b) == up){
        sv[i] = b; sv[j] = a;
        int ti = si[i]; si[i] = si[j]; si[j] = ti;
      }
    }
  }
  __syncthreads();
  for (int i = tid; i < LV; i += 1024) sv[i] = expf(sv[i] - ymax) / denom;
  __syncthreads();
  if (tid == 0){
    float c = 0.0f; int kc = LV;
    for (int j = 0; j < LV; ++j){
      c += sv[j];
      if (!((double)c <= 0.6)){ kc = j; break; }
    }
    *kcount = kc;
  }
  __syncthreads();
  for (int i = tid; i < LV; i += 1024) ord[i] = si[i];
}

// ---------------- output writer ----------------
__global__ __launch_bounds__(256)
void writer_kernel(const float* __restrict__ vis, const int* __restrict__ ord,
                   const int* __restrict__ kc, float* __restrict__ out)
{
  const int j = blockIdx.x;
  float4* dst = (float4*)(out + (size_t)j * DIM);
  if (j < kc[0]){
    const float4* src = (const float4*)(vis + (size_t)ord[j] * DIM);
    for (int i = threadIdx.x; i < DIM/4; i += 256) dst[i] = src[i];
  } else {
    const float4 z4 = make_float4(0.f,0.f,0.f,0.f);
    for (int i = threadIdx.x; i < DIM/4; i += 256) dst[i] = z4;
  }
}

// ---------------- launch ----------------
extern "C" void kernel_launch(void* const* d_in, const int* in_sizes, int n_in,
                              void* d_out, int out_size, void* d_ws, size_t ws_size,
                              hipStream_t stream)
{
  (void)in_sizes; (void)n_in; (void)out_size;
  const float* vis  = (const float*)d_in[0];
  const float* txt  = (const float*)d_in[1];
  const float* mask = (const float*)d_in[2];
  const float* noise= (const float*)d_in[3];
  const float* Wq = (const float*)d_in[4];  const float* bq = (const float*)d_in[5];
  const float* Wk = (const float*)d_in[6];  const float* bk = (const float*)d_in[7];
  const float* Wv = (const float*)d_in[8];  const float* bv = (const float*)d_in[9];
  const float* Wo = (const float*)d_in[10]; const float* bo = (const float*)d_in[11];
  const float* lw = (const float*)d_in[12]; const float* lb = (const float*)d_in[13];
  const float* W1 = (const float*)d_in[14]; const float* b1 = (const float*)d_in[15];
  const float* W2 = (const float*)d_in[16]; const float* b2 = (const float*)d_in[17];
  float* out = (float*)d_out;
  const dim3 blk(256);
  const size_t MiB = 1u << 20;

  // pick Hc (heads per attention group) for the new path
  int Hc = 0;
  for (int h = 16; h >= 1; h >>= 1){
    size_t need = (192 + 16 * (size_t)h) * MiB;
    if (need <= ws_size){ Hc = h; break; }
  }

  if (Hc > 0){
    // ---------------- canonical pre-split + glds GEMM -----------------------
    char* B0 = (char*)d_ws;
    u16* WSh  = (u16*)(B0 + 0);          u16* WSl  = (u16*)(B0 + 32*MiB);
    float* TMPf = (float*)(B0 + 64*MiB);
    u16* QCh  = (u16*)(B0 + 96*MiB);     u16* QCl  = (u16*)(B0 + 112*MiB);
    u16* VCh  = (u16*)(B0 + 128*MiB);    u16* VCl  = (u16*)(B0 + 144*MiB);
    u16* TCh  = (u16*)(B0 + 160*MiB);    u16* TCl  = (u16*)(B0 + 168*MiB);
    float* KF  = (float*)(B0 + 176*MiB);
    float* VTF = (float*)(B0 + 192*MiB);
    u16* VTCh = (u16*)(B0 + 176*MiB);    u16* VTCl = (u16*)(B0 + 184*MiB);
    float* Lf  = (float*)(B0 + 192*MiB);
    u16* PCh  = (u16*)(B0 + (192 + (size_t)Hc*8)*MiB);
    u16* PCl  = (u16*)(B0 + (192 + (size_t)Hc*12)*MiB);
    float* H1f = (float*)(B0 + 128*MiB);
    u16* XNh  = (u16*)(B0 + 96*MiB);     u16* XNl  = (u16*)(B0 + 112*MiB);
    float* SCf = (float*)(B0 + 192*MiB);
    int* ORD = (int*)(SCf + LV);
    int* KCp = ORD + LV;

    // canonicalize inputs (Kc=4096 -> 128 k-tiles of 32, ktsh=7)
    repack_kernel<<<dim3(4096), blk, 0, stream>>>(vis, VCh, VCl, 4096, 7);
    repack_kernel<<<dim3(2048), blk, 0, stream>>>(txt, TCh, TCl, 4096, 7);
    // Q = vis @ Wq^T + bq
    repack_kernel<<<dim3(8192), blk, 0, stream>>>(Wq, WSh, WSl, 4096, 7);
    mgemm<0,0><<<dim3(512,1,1), blk, 0, stream>>>(VCh, VCl, 128, 0, WSh, WSl, 128, 0,
        TMPf, 4096, 0, bq, 32, 128, 0, 0, 1.0f);
    // K
    repack_kernel<<<dim3(8192), blk, 0, stream>>>(Wk, WSh, WSl, 4096, 7);
    mgemm<0,0><<<dim3(256,1,1), blk, 0, stream>>>(TCh, TCl, 128, 0, WSh, WSl, 128, 0,
        KF, 4096, 0, bk, 32, 128, 0, 0, 1.0f);
    // V (transposed out: Vt[4096][1024])
    repack_kernel<<<dim3(8192), blk, 0, stream>>>(Wv, WSh, WSl, 4096, 7);
    mgemm<0,1><<<dim3(256,1,1), blk, 0, stream>>>(TCh, TCl, 128, 0, WSh, WSl, 128, 0,
        VTF, 1024, 0, bv, 32, 128, 0, 0, 1.0f);
    // canonicalize intermediates
    repack_kernel<<<dim3(4096), blk, 0, stream>>>(TMPf, QCh, QCl, 4096, 7);
    repack_kernel<<<dim3(2048), blk, 0, stream>>>(KF, TCh, TCl, 4096, 7);
    repack_kernel<<<dim3(2048), blk, 0, stream>>>(VTF, VTCh, VTCl, 1024, 5);
    // attention, Hc heads per group
    const int NG = NHD / Hc;
    for (int g = 0; g < NG; ++g){
      mgemm<0,0><<<dim3(128,1,Hc), blk, 0, stream>>>(QCh, QCl, 128, 0, TCh, TCl, 128, 0,
          Lf, 1024, 2097152ll, mask, 8, 8, g*Hc*8, 8, 0.0625f);
      softmax_pack<<<dim3(Hc*2048), dim3(128), 0, stream>>>(Lf, PCh, PCl);
      mgemm<0,0><<<dim3(32,1,Hc), blk, 0, stream>>>(PCh, PCl, 32, 2097152ll,
          VTCh + (long long)g*Hc*262144, VTCl + (long long)g*Hc*262144, 32, 262144ll,
          TMPf + (long long)g*Hc*256, 4096, 256, nullptr, 2, 32, 0, 0, 1.0f);
    }
    // ctx -> canonical (into vis_c slot)
    repack_kernel<<<dim3(4096), blk, 0, stream>>>(TMPf, VCh, VCl, 4096, 7);
    // attn_out = ctx @ Wo^T + bo  (into TMPf)
    repack_kernel<<<dim3(8192), blk, 0, stream>>>(Wo, WSh, WSl, 4096, 7);
    mgemm<0,0><<<dim3(512,1,1), blk, 0, stream>>>(VCh, VCl, 128, 0, WSh, WSl, 128, 0,
        TMPf, 4096, 0, bo, 32, 128, 0, 0, 1.0f);
    // residual + LN -> xn canonical
    ln_kernel<1><<<dim3(LV), blk, 0, stream>>>(vis, TMPf, nullptr, XNh, XNl, lw, lb);
    // MLP hidden (two N-halves of W1), fused exact gelu
    repack_kernel<<<dim3(8192), blk, 0, stream>>>(W1, WSh, WSl, 4096, 7);
    mgemm<1,0><<<dim3(512,1,1), blk, 0, stream>>>(XNh, XNl, 128, 0, WSh, WSl, 128, 0,
        H1f, 8192, 0, b1, 32, 128, 0, 0, 1.0f);
    repack_kernel<<<dim3(8192), blk, 0, stream>>>(W1 + 16777216ll, WSh, WSl, 4096, 7);
    mgemm<1,0><<<dim3(512,1,1), blk, 0, stream>>>(XNh, XNl, 128, 0, WSh, WSl, 128, 0,
        H1f + 4096, 8192, 0, b1 + 4096, 32, 128, 0, 0, 1.0f);
    // scores, selection, output
    score_kernel<<<dim3(LV), blk, 0, stream>>>(H1f, W2, b2, noise, SCf);
    select_kernel<<<dim3(1), dim3(1024), 0, stream>>>(SCf, ORD, KCp);
    writer_kernel<<<dim3(LV), blk, 0, stream>>>(vis, ORD, KCp, out);
    return;
  }

  // ---------------- fallback path (R3, verified) ----------------------------
  float* ws = (float*)d_ws;
  const long long OQ  = 0;
  const long long OK_ = (long long)LV * DIM;
  const long long OV  = OK_ + (long long)LT * DIM;
  const long long OC  = OV  + (long long)LT * DIM;
  const long long OL  = OC  + (long long)LV * DIM;
  const long long LSTRIDE = (long long)LV * LT;
  int Hf = 16;
  while (Hf > 1){
    size_t need = (size_t)(OL + (long long)Hf * LSTRIDE + 8192) * 4;
    if (need <= ws_size) break;
    Hf >>= 1;
  }
  float* Qw  = ws + OQ;
  float* Kw  = ws + OK_;
  float* Vt  = ws + OV;
  float* Cw  = ws + OC;
  float* Lw  = ws + OL;
  float* H1w = ws + OK_;
  float* SCw = ws + OL + (long long)Hf * LSTRIDE;
  int*   ORDw = (int*)(SCw + LV);
  int*   KCw  = ORDw + LV;

  mgemm_fb<0,0><<<dim3(DIM/128, LV/128, 1), blk, 0, stream>>>(vis,0,DIM, Wq,0,DIM, Qw,0,DIM, bq, DIM, 1.0f);
  mgemm_fb<0,0><<<dim3(DIM/128, LT/128, 1), blk, 0, stream>>>(txt,0,DIM, Wk,0,DIM, Kw,0,DIM, bk, DIM, 1.0f);
  mgemm_fb<0,1><<<dim3(DIM/128, LT/128, 1), blk, 0, stream>>>(txt,0,DIM, Wv,0,DIM, Vt,0,LT, bv, DIM, 1.0f);
  for (int g = 0; g < NHD/Hf; ++g){
    const long long ho = (long long)g * Hf * HDD;
    mgemm_fb<0,0><<<dim3(LT/128, LV/128, Hf), blk, 0, stream>>>(
        Qw+ho, HDD, DIM,  Kw+ho, HDD, DIM,  Lw, LSTRIDE, LT,  mask, HDD, 0.0625f);
    softmax_fb<<<dim3(Hf*LV), blk, 0, stream>>>(Lw);
    mgemm_fb<0,0><<<dim3(HDD/128, LV/128, Hf), blk, 0, stream>>>(
        Lw, LSTRIDE, LT,  Vt + (ho*(long long)LT), (long long)HDD*LT, LT,
        Cw+ho, HDD, DIM,  nullptr, LT, 1.0f);
  }
  mgemm_fb<0,0><<<dim3(DIM/128, LV/128, 1), blk, 0, stream>>>(Cw,0,DIM, Wo,0,DIM, Qw,0,DIM, bo, DIM, 1.0f);
  ln_kernel<0><<<dim3(LV), blk, 0, stream>>>(vis, Qw, Qw, nullptr, nullptr, lw, lb);
  mgemm_fb<1,0><<<dim3(MLPH/128, LV/128, 1), blk, 0, stream>>>(Qw,0,DIM, W1,0,DIM, H1w,0,MLPH, b1, DIM, 1.0f);
  score_kernel<<<dim3(LV), blk, 0, stream>>>(H1w, W2, b2, noise, SCw);
  select_kernel<<<dim3(1), dim3(1024), 0, stream>>>(SCw, ORDw, KCw);
  writer_kernel<<<dim3(LV), blk, 0, stream>>>(vis, ORDw, KCw, out);
}